// Round 6
// baseline (96.240 us; speedup 1.0000x reference)
//
#include <hip/hip_runtime.h>

// DCT2D_Layer: 8x8 block DCT-II (norm=None) + zigzag reorder.
// img [16,3,512,512] f32 -> out [16, 3*64, 64, 64] f32
// v5b: v4 compute (hoisted loads, scalarized butterflies, in-place col DCT)
//     + LDS-staged stores: 4 chunks x 16 planes through 16KB LDS; each wave
//     stores whole 1KB plane regions as float4 nontemporal stores (vs v4's
//     64 scattered 256B scalar wave-stores). Occupancy unchanged (12 w/CU).
//     (v5 fix: native ext_vector float4 for the nontemporal builtin.)

typedef float floatx4 __attribute__((ext_vector_type(4)));

// 2*cos(m*pi/16)
#define K1 1.9615705608064609f
#define K2 1.8477590650225735f
#define K3 1.6629392246050905f
#define K4 1.4142135623730951f
#define K5 1.1111404660392044f
#define K6 0.7653668647301796f
#define K7 0.3901806440322565f

// Unnormalized DCT-II, factor 2: y[k] = 2*sum_n x[n] cos(pi*(2n+1)k/16)
// Reads all inputs into temps first -> safe for in-place use (y == x).
#define DCT8(x0,x1,x2,x3,x4,x5,x6,x7, y0,y1,y2,y3,y4,y5,y6,y7) do {        \
    float s0=(x0)+(x7), s1=(x1)+(x6), s2=(x2)+(x5), s3=(x3)+(x4);          \
    float d0=(x0)-(x7), d1=(x1)-(x6), d2=(x2)-(x5), d3=(x3)-(x4);          \
    float e0=s0+s3, e1=s1+s2, o0=s0-s3, o1=s1-s2;                          \
    y0 = 2.0f*(e0+e1);                                                     \
    y4 = K4*(e0-e1);                                                       \
    y2 = K2*o0 + K6*o1;                                                    \
    y6 = K6*o0 - K2*o1;                                                    \
    y1 = K1*d0 + K3*d1 + K5*d2 + K7*d3;                                    \
    y3 = K3*d0 - K7*d1 - K1*d2 - K5*d3;                                    \
    y5 = K5*d0 - K1*d1 + K7*d2 + K3*d3;                                    \
    y7 = K7*d0 - K5*d1 + K3*d2 - K1*d3;                                    \
} while (0)

#define LOADROW(r)                                                          \
    const float4 L##r##a = *reinterpret_cast<const float4*>(src + (r)*512); \
    const float4 L##r##b = *reinterpret_cast<const float4*>(src + (r)*512 + 4);

#define ROWDCT(r)                                                          \
    DCT8(L##r##a.x,L##r##a.y,L##r##a.z,L##r##a.w,                          \
         L##r##b.x,L##r##b.y,L##r##b.z,L##r##b.w,                          \
         t##r##0,t##r##1,t##r##2,t##r##3,t##r##4,t##r##5,t##r##6,t##r##7);

// In-place column DCT for column v.
#define COLDCT(v)                                                          \
    DCT8(t0##v,t1##v,t2##v,t3##v,t4##v,t5##v,t6##v,t7##v,                  \
         t0##v,t1##v,t2##v,t3##v,t4##v,t5##v,t6##v,t7##v);

// Stage z value t{u}{v} (zigzag plane p) into the current 16-plane chunk.
// addr = (p&15)*256 + tid_in_wg : bank = tid%32, 2 lanes/bank -> free.
#define LW(u,v,p) lds[((p)&15)*256 + tx] = t##u##v;

// Drain chunk c: each wave stores 4 whole plane regions (1KB each) as
// one float4 per lane, nontemporal.
#define DRAIN(c) do {                                                      \
    __syncthreads();                                                       \
    _Pragma("unroll")                                                      \
    for (int i = 0; i < 4; ++i) {                                          \
        const int pl = (tx >> 6) * 4 + i;            /* wave-uniform */    \
        const floatx4 vv =                                                 \
            *reinterpret_cast<const floatx4*>(&lds[pl*256 + lane*4]);      \
        __builtin_nontemporal_store(vv,                                    \
            reinterpret_cast<floatx4*>(dstc + (size_t)((c)*16+pl)*4096     \
                                       + lane*4));                         \
    }                                                                      \
    __syncthreads();                                                       \
} while (0)

__global__ __launch_bounds__(256) void dct2d_zigzag_kernel(
    const float* __restrict__ img, float* __restrict__ out)
{
    __shared__ float lds[16 * 256];   // 16KB: 16 planes x (4 bi-rows x 64 bj)

    const int tx   = threadIdx.x;          // 0..255
    const int lane = tx & 63;              // bj
    const int w    = tx >> 6;              // bi offset within wg (wave id)
    const int g    = blockIdx.x;           // 0..767
    const int bc   = g >> 4;               // b*3 + ch, 0..47
    const int bi0  = (g & 15) * 4;         // base block row
    const int bi   = bi0 + w;

    // Input: img[bc, bi*8 + r, bj*8 + x]; channel plane = 512*512
    const float* __restrict__ src =
        img + (size_t)bc * 262144 + (size_t)bi * 4096 + (size_t)lane * 8;

    // Output chunk base: out[bc*64 + p, bi0.., :]; plane = 4096 floats
    float* __restrict__ dstc =
        out + (size_t)bc * 262144 + (size_t)bi0 * 64;

    LOADROW(0) LOADROW(1) LOADROW(2) LOADROW(3)
    LOADROW(4) LOADROW(5) LOADROW(6) LOADROW(7)

    float t00,t01,t02,t03,t04,t05,t06,t07;
    float t10,t11,t12,t13,t14,t15,t16,t17;
    float t20,t21,t22,t23,t24,t25,t26,t27;
    float t30,t31,t32,t33,t34,t35,t36,t37;
    float t40,t41,t42,t43,t44,t45,t46,t47;
    float t50,t51,t52,t53,t54,t55,t56,t57;
    float t60,t61,t62,t63,t64,t65,t66,t67;
    float t70,t71,t72,t73,t74,t75,t76,t77;

    ROWDCT(0) ROWDCT(1) ROWDCT(2) ROWDCT(3)
    ROWDCT(4) ROWDCT(5) ROWDCT(6) ROWDCT(7)

    COLDCT(0) COLDCT(1) COLDCT(2) COLDCT(3)
    COLDCT(4) COLDCT(5) COLDCT(6) COLDCT(7)

    // Chunk 0: zigzag planes 0..15 -> (u,v) entries
    LW(0,0, 0) LW(0,1, 1) LW(1,0, 2) LW(2,0, 3) LW(1,1, 4) LW(0,2, 5)
    LW(0,3, 6) LW(1,2, 7) LW(2,1, 8) LW(3,0, 9) LW(4,0,10) LW(3,1,11)
    LW(2,2,12) LW(1,3,13) LW(0,4,14) LW(0,5,15)
    DRAIN(0);

    // Chunk 1: planes 16..31
    LW(1,4,16) LW(2,3,17) LW(3,2,18) LW(4,1,19) LW(5,0,20) LW(6,0,21)
    LW(5,1,22) LW(4,2,23) LW(3,3,24) LW(2,4,25) LW(1,5,26) LW(0,6,27)
    LW(0,7,28) LW(1,6,29) LW(2,5,30) LW(3,4,31)
    DRAIN(1);

    // Chunk 2: planes 32..47
    LW(4,3,32) LW(5,2,33) LW(6,1,34) LW(7,0,35) LW(7,1,36) LW(6,2,37)
    LW(5,3,38) LW(4,4,39) LW(3,5,40) LW(2,6,41) LW(1,7,42) LW(2,7,43)
    LW(3,6,44) LW(4,5,45) LW(5,4,46) LW(6,3,47)
    DRAIN(2);

    // Chunk 3: planes 48..63
    LW(7,2,48) LW(7,3,49) LW(6,4,50) LW(5,5,51) LW(4,6,52) LW(3,7,53)
    LW(4,7,54) LW(5,6,55) LW(6,5,56) LW(7,4,57) LW(7,5,58) LW(6,6,59)
    LW(5,7,60) LW(6,7,61) LW(7,6,62) LW(7,7,63)
    DRAIN(3);
}

extern "C" void kernel_launch(void* const* d_in, const int* in_sizes, int n_in,
                              void* d_out, int out_size, void* d_ws, size_t ws_size,
                              hipStream_t stream)
{
    const float* img = (const float*)d_in[0];
    float* out = (float*)d_out;
    // 768 wgs x 256 threads; wg = (bc, 4 consecutive bi rows) -> 3 wg/CU
    dct2d_zigzag_kernel<<<768, 256, 0, stream>>>(img, out);
}